// Round 8
// baseline (131.078 us; speedup 1.0000x reference)
//
#include <hip/hip_runtime.h>
#include <math.h>

#define T_SEQ 2048
#define NH    16
#define HD    64
#define DIM   1024
#define WIN   256
#define REP_P 8   // prep repetitions: instrumentation (raise above ~43us fills)

typedef __attribute__((ext_vector_type(4))) float f32x4;
typedef __attribute__((ext_vector_type(8))) short s16x8;
typedef unsigned short u16;

static __device__ __forceinline__ u16 f2bf(float f) {
    unsigned u = __builtin_bit_cast(unsigned, f);
    u += 0x7fff + ((u >> 16) & 1);   // RNE; inputs finite
    return (u16)(u >> 16);
}

static __device__ __forceinline__ int fV(int d) { return (d & 7) ^ ((d >> 3) & 7); }

static __device__ __forceinline__ void gload16(const void* g, void* l) {
    __builtin_amdgcn_global_load_lds(
        (const __attribute__((address_space(1))) unsigned int*)g,
        (__attribute__((address_space(3))) unsigned int*)l, 16, 0, 0);
}

// ---------------------------------------------------------------------------
// Fused prep kernel, repeated REP_P times internally (deterministic —
// identical work and output each rep) so its counters surface in top-5.
// blocks [0,256): W transpose+bf16. blocks [256,768): attention.
// ---------------------------------------------------------------------------
__global__ __launch_bounds__(256) void prep_kernel(const float* __restrict__ W,
                                                   u16* __restrict__ Wt,
                                                   const float* __restrict__ qg,
                                                   const float* __restrict__ kg,
                                                   const float* __restrict__ vg,
                                                   u16* __restrict__ y) {
    __shared__ __align__(16) char smem[4 * 16 * 128 + 2 * 64 * 128];  // 24KB
    const int bid = (int)blockIdx.x;
    const int t   = threadIdx.x;

    if (bid < 256) {
#pragma unroll 1
        for (int rep = 0; rep < REP_P; ++rep) {
            float(*sT)[69] = (float(*)[69])smem;
            const int k0 = (bid & 15) * 64;
            const int n0 = (bid >> 4) * 64;
#pragma unroll
            for (int i = 0; i < 4; ++i) {
                const int idx = i * 256 + t;
                const int kr = idx >> 4, c4 = (idx & 15) * 4;
                float4 v = *(const float4*)(W + (size_t)(k0 + kr) * DIM + n0 + c4);
                sT[kr][c4] = v.x; sT[kr][c4 + 1] = v.y; sT[kr][c4 + 2] = v.z; sT[kr][c4 + 3] = v.w;
            }
            __syncthreads();
#pragma unroll
            for (int i = 0; i < 2; ++i) {
                const int idx = i * 256 + t;
                const int nr = idx >> 3, ch = (idx & 7) * 8;
                s16x8 o;
#pragma unroll
                for (int e = 0; e < 8; ++e) o[e] = f2bf(sT[ch + e][nr]);
                *(s16x8*)(Wt + (size_t)(n0 + nr) * DIM + k0 + ch) = o;
            }
            __syncthreads();  // rep boundary: sT reads done before next overwrite
        }
        return;
    }

#pragma unroll 1
    for (int rep = 0; rep < REP_P; ++rep) {
        char* sK  = smem;
        char* sV  = smem + 64 * 128;
        char* sPb = smem + 2 * 64 * 128;

        const int ab   = bid - 256;
        const int lane = t & 63;
        const int w    = t >> 6;
        const int q0   = (ab & 31) * 64;
        const int h    = ab >> 5;
        const size_t headBase = (size_t)h * T_SEQ * HD;

        const int lr = lane & 15;
        const int lg = lane >> 4;

        s16x8 qf[2];
        {
            const float* qrow = qg + headBase + (size_t)(q0 + w * 16 + lr) * HD + lg * 8;
#pragma unroll
            for (int s = 0; s < 2; ++s) {
                float4 a = *(const float4*)(qrow + 32 * s);
                float4 b = *(const float4*)(qrow + 32 * s + 4);
                s16x8 f;
                f[0] = f2bf(a.x); f[1] = f2bf(a.y); f[2] = f2bf(a.z); f[3] = f2bf(a.w);
                f[4] = f2bf(b.x); f[5] = f2bf(b.y); f[6] = f2bf(b.z); f[7] = f2bf(b.w);
                qf[s] = f;
            }
        }

        f32x4 o[4];
#pragma unroll
        for (int i = 0; i < 4; ++i) o[i] = (f32x4){0.f, 0.f, 0.f, 0.f};
        float lsum[4] = {0.f, 0.f, 0.f, 0.f};

        int lo = q0 - (WIN - 1);
        if (lo < 0) lo = 0;
        const int kc0 = lo & ~63;

        const int srow = t >> 2;
        const int sd0  = (t & 3) * 16;

        for (int kc = kc0; kc <= q0; kc += 64) {
            __syncthreads();
            {
                const float* ksrc = kg + headBase + (size_t)(kc + srow) * HD + sd0;
                float4 k0 = *(const float4*)(ksrc);
                float4 k1 = *(const float4*)(ksrc + 4);
                float4 k2 = *(const float4*)(ksrc + 8);
                float4 k3 = *(const float4*)(ksrc + 12);
                s16x8 c0, c1;
                c0[0] = f2bf(k0.x); c0[1] = f2bf(k0.y); c0[2] = f2bf(k0.z); c0[3] = f2bf(k0.w);
                c0[4] = f2bf(k1.x); c0[5] = f2bf(k1.y); c0[6] = f2bf(k1.z); c0[7] = f2bf(k1.w);
                c1[0] = f2bf(k2.x); c1[1] = f2bf(k2.y); c1[2] = f2bf(k2.z); c1[3] = f2bf(k2.w);
                c1[4] = f2bf(k3.x); c1[5] = f2bf(k3.y); c1[6] = f2bf(k3.z); c1[7] = f2bf(k3.w);
                const int swz = (srow & 7) << 4;
                *(s16x8*)(sK + srow * 128 + ((sd0 * 2) ^ swz))      = c0;
                *(s16x8*)(sK + srow * 128 + ((sd0 * 2 + 16) ^ swz)) = c1;

                const float* vsrc = vg + headBase + (size_t)(kc + srow) * HD + sd0;
                float4 v0 = *(const float4*)(vsrc);
                float4 v1 = *(const float4*)(vsrc + 4);
                float4 v2 = *(const float4*)(vsrc + 8);
                float4 v3 = *(const float4*)(vsrc + 12);
                float vv[16] = {v0.x, v0.y, v0.z, v0.w, v1.x, v1.y, v1.z, v1.w,
                                v2.x, v2.y, v2.z, v2.w, v3.x, v3.y, v3.z, v3.w};
#pragma unroll
                for (int e = 0; e < 16; ++e) {
                    const int d = sd0 + e;
                    *(u16*)(sV + d * 128 + ((srow * 2) ^ (fV(d) << 4))) = f2bf(vv[e]);
                }
            }
            __syncthreads();

            char* pw = sPb + w * 16 * 128;
#pragma unroll
            for (int kt = 0; kt < 4; ++kt) {
                const int krow = kt * 16 + lr;
                const int kswz = (krow & 7) << 4;
                s16x8 kf0 = *(const s16x8*)(sK + krow * 128 + ((lg * 16) ^ kswz));
                s16x8 kf1 = *(const s16x8*)(sK + krow * 128 + ((lg * 16 + 64) ^ kswz));
                f32x4 s = (f32x4){0.f, 0.f, 0.f, 0.f};
                s = __builtin_amdgcn_mfma_f32_16x16x32_bf16(qf[0], kf0, s, 0, 0, 0);
                s = __builtin_amdgcn_mfma_f32_16x16x32_bf16(qf[1], kf1, s, 0, 0, 0);
                const int key = kc + kt * 16 + lr;
#pragma unroll
                for (int r = 0; r < 4; ++r) {
                    const int qrow = q0 + w * 16 + lg * 4 + r;
                    float pv = 0.f;
                    if (key <= qrow && key > qrow - WIN) pv = __expf(s[r] * 0.125f);
                    lsum[r] += pv;
                    const int prow = lg * 4 + r;
                    *(u16*)(pw + prow * 128 + ((kt * 32 + lr * 2) ^ ((prow & 7) << 4))) = f2bf(pv);
                }
            }

            s16x8 pf0 = *(const s16x8*)(pw + lr * 128 + ((lg * 16) ^ ((lr & 7) << 4)));
            s16x8 pf1 = *(const s16x8*)(pw + lr * 128 + ((lg * 16 + 64) ^ ((lr & 7) << 4)));
#pragma unroll
            for (int td = 0; td < 4; ++td) {
                const int drow = td * 16 + lr;
                const int vswz = fV(drow) << 4;
                s16x8 vf0 = *(const s16x8*)(sV + drow * 128 + ((lg * 16) ^ vswz));
                s16x8 vf1 = *(const s16x8*)(sV + drow * 128 + ((lg * 16 + 64) ^ vswz));
                o[td] = __builtin_amdgcn_mfma_f32_16x16x32_bf16(pf0, vf0, o[td], 0, 0, 0);
                o[td] = __builtin_amdgcn_mfma_f32_16x16x32_bf16(pf1, vf1, o[td], 0, 0, 0);
            }
        }

#pragma unroll
        for (int m = 1; m < 16; m <<= 1) {
#pragma unroll
            for (int r = 0; r < 4; ++r) lsum[r] += __shfl_xor(lsum[r], m, 64);
        }
        float rl[4];
#pragma unroll
        for (int r = 0; r < 4; ++r) rl[r] = 1.f / lsum[r];
#pragma unroll
        for (int td = 0; td < 4; ++td)
#pragma unroll
            for (int r = 0; r < 4; ++r)
                y[(size_t)(q0 + w * 16 + lg * 4 + r) * DIM + h * HD + td * 16 + lr] =
                    f2bf(o[td][r] * rl[r]);
        __syncthreads();  // rep boundary
    }
}

// ---------------------------------------------------------------------------
// proj: out = y @ W. BM=128 BN=64 BK=64, 4 waves (2x2), wave-tile 64x32.
// grid = 256 blocks = 1/CU -- FULL chip (R7's 128-block version left half
// idle; counters showed pure starvation, not conflicts). Triple-buffered
// counted-vmcnt pipeline (R7 structure, measured 12.97us at half-chip):
//   STAGE(t+2) ; vmcnt(12) ; s_barrier ; ds_read+MFMA(setprio) ; s_barrier
// LDS 72KB. XCD-chunked swizzle: 2 M-panels x 16 N-panels per XCD (2.5MB L2).
// ---------------------------------------------------------------------------
__global__ __launch_bounds__(256) void proj_kernel(const u16* __restrict__ A,
                                                   const u16* __restrict__ Bt,
                                                   float* __restrict__ out) {
    __shared__ __align__(16) char sA[3][128 * 128];  // [m][k] bf16, 16KB/buf
    __shared__ __align__(16) char sB[3][64 * 128];   // [n][k] bf16,  8KB/buf

    const int t    = threadIdx.x;
    const int lane = t & 63;
    const int w    = t >> 6;
    const int wr   = w >> 1, wc = w & 1;
    const int lr   = lane & 15, lg = lane >> 4;

    // XCD-chunked bijective swizzle (nwg=256, 8 XCDs, q=32)
    const int id   = (int)blockIdx.x;
    const int wgid = (id & 7) * 32 + (id >> 3);
    const int m0   = (wgid >> 4) * 128;   // 16 M-panels
    const int n0   = (wgid & 15) * 64;    // 16 N-panels

    f32x4 acc[4][2];
#pragma unroll
    for (int i = 0; i < 4; ++i)
#pragma unroll
        for (int j = 0; j < 2; ++j) acc[i][j] = (f32x4){0.f, 0.f, 0.f, 0.f};

    // staging: A pass pi=p*4+w (p<4) covers rows [pi*8, pi*8+8);
    //          B pass pi=p*4+w (p<2) likewise. lane -> row +(lane>>3), chunk lane&7.
    const int sRow = lane >> 3;
    const int sCh  = lane & 7;

#define STAGE(buf, k0)                                                                 \
    do {                                                                               \
        _Pragma("unroll") for (int p = 0; p < 4; ++p) {                                \
            const int pi  = p * 4 + w;                                                 \
            const int row = pi * 8 + sRow;                                             \
            gload16(A + (size_t)(m0 + row) * DIM + (k0) + ((sCh ^ (row & 7)) << 3),    \
                    sA[buf] + pi * 1024);                                              \
        }                                                                              \
        _Pragma("unroll") for (int p = 0; p < 2; ++p) {                                \
            const int pi  = p * 4 + w;                                                 \
            const int row = pi * 8 + sRow;                                             \
            gload16(Bt + (size_t)(n0 + row) * DIM + (k0) + ((sCh ^ (row & 7)) << 3),   \
                    sB[buf] + pi * 1024);                                              \
        }                                                                              \
    } while (0)

    STAGE(0, 0);
    STAGE(1, 64);

#pragma unroll
    for (int kt = 0; kt < DIM / 64; ++kt) {
        const int cur  = kt % 3;
        const int nxt  = (kt + 2) % 3;
        const int knxt = ((kt + 2) & 15) * 64;  // tail wraps: stale, harmless

        STAGE(nxt, knxt);                       // dest buf reads done (kt-1 end barrier)
        asm volatile("s_waitcnt vmcnt(12)" ::: "memory");  // own tile-kt landed
        __builtin_amdgcn_s_barrier();           // => ALL waves' tile-kt landed

        s16x8 af[2][4], bfr[2][2];
#pragma unroll
        for (int kh = 0; kh < 2; ++kh) {
#pragma unroll
            for (int mi = 0; mi < 4; ++mi) {
                const int row = wr * 64 + mi * 16 + lr;
                const int cc  = kh * 4 + lg;
                af[kh][mi] = *(const s16x8*)(sA[cur] + row * 128 + ((cc ^ (row & 7)) << 4));
            }
#pragma unroll
            for (int ni = 0; ni < 2; ++ni) {
                const int row = wc * 32 + ni * 16 + lr;
                const int cc  = kh * 4 + lg;
                bfr[kh][ni] = *(const s16x8*)(sB[cur] + row * 128 + ((cc ^ (row & 7)) << 4));
            }
        }
        __builtin_amdgcn_s_setprio(1);
#pragma unroll
        for (int kh = 0; kh < 2; ++kh)
#pragma unroll
            for (int mi = 0; mi < 4; ++mi)
#pragma unroll
                for (int ni = 0; ni < 2; ++ni)
                    acc[mi][ni] = __builtin_amdgcn_mfma_f32_16x16x32_bf16(
                        af[kh][mi], bfr[kh][ni], acc[mi][ni], 0, 0, 0);
        __builtin_amdgcn_s_setprio(0);
        __builtin_amdgcn_s_barrier();           // buf[cur] reads done before overwrite
    }
#undef STAGE

    asm volatile("s_waitcnt vmcnt(0)" ::: "memory");  // drain stale tail gloads

#pragma unroll
    for (int mi = 0; mi < 4; ++mi)
#pragma unroll
        for (int ni = 0; ni < 2; ++ni)
#pragma unroll
            for (int r = 0; r < 4; ++r)
                out[(size_t)(m0 + wr * 64 + mi * 16 + lg * 4 + r) * DIM +
                    n0 + wc * 32 + ni * 16 + lr] = acc[mi][ni][r];
}

extern "C" void kernel_launch(void* const* d_in, const int* in_sizes, int n_in,
                              void* d_out, int out_size, void* d_ws, size_t ws_size,
                              hipStream_t stream) {
    const float* q = (const float*)d_in[0];
    const float* k = (const float*)d_in[1];
    const float* v = (const float*)d_in[2];
    const float* W = (const float*)d_in[3];
    float* out = (float*)d_out;
    u16* y_bf = (u16*)d_ws;                       // (T, DIM) bf16 = 4MB
    u16* Wt   = (u16*)d_ws + (size_t)T_SEQ * DIM; // (DIM, DIM) bf16 = 2MB

    prep_kernel<<<768, 256, 0, stream>>>(W, Wt, q, k, v, y_bf);
    proj_kernel<<<256, 256, 0, stream>>>(y_bf, Wt, out);
}

// Round 9
// 36.529 us; speedup vs baseline: 3.5884x; 3.5884x over previous
//
#include <hip/hip_runtime.h>
#include <math.h>

#define T_SEQ 2048
#define NH    16
#define HD    64
#define DIM   1024
#define WIN   256

typedef __attribute__((ext_vector_type(4))) float f32x4;
typedef __attribute__((ext_vector_type(8))) short s16x8;
typedef unsigned short u16;

static __device__ __forceinline__ u16 f2bf(float f) {
    unsigned u = __builtin_bit_cast(unsigned, f);
    u += 0x7fff + ((u >> 16) & 1);   // RNE; inputs finite
    return (u16)(u >> 16);
}

static __device__ __forceinline__ int fV(int d) { return (d & 7) ^ ((d >> 3) & 7); }

static __device__ __forceinline__ void gload16(const void* g, void* l) {
    __builtin_amdgcn_global_load_lds(
        (const __attribute__((address_space(1))) unsigned int*)g,
        (__attribute__((address_space(3))) unsigned int*)l, 16, 0, 0);
}

// ---------------------------------------------------------------------------
// Fused prep kernel. blocks [0,256): W transpose+bf16. blocks [256,768): attn.
// Attention: T14 async-STAGE split -- chunk t+1's K/V global loads issue into
// registers BEFORE chunk t's compute; f2bf+LDS-write lands after the barrier.
// V-transpose staged as u32 key-pairs (8 DS writes/thread, 2 lanes/bank=free).
// ---------------------------------------------------------------------------
__global__ __launch_bounds__(256) void prep_kernel(const float* __restrict__ W,
                                                   u16* __restrict__ Wt,
                                                   const float* __restrict__ qg,
                                                   const float* __restrict__ kg,
                                                   const float* __restrict__ vg,
                                                   u16* __restrict__ y) {
    __shared__ __align__(16) char smem[4 * 16 * 128 + 2 * 64 * 128];  // 24KB
    const int bid = (int)blockIdx.x;
    const int t   = threadIdx.x;

    if (bid < 256) {
        // ---- wconv: W (K x N fp32) -> Wt (N x K bf16) ----
        float(*sT)[69] = (float(*)[69])smem;
        const int k0 = (bid & 15) * 64;
        const int n0 = (bid >> 4) * 64;
#pragma unroll
        for (int i = 0; i < 4; ++i) {
            const int idx = i * 256 + t;
            const int kr = idx >> 4, c4 = (idx & 15) * 4;
            float4 v = *(const float4*)(W + (size_t)(k0 + kr) * DIM + n0 + c4);
            sT[kr][c4] = v.x; sT[kr][c4 + 1] = v.y; sT[kr][c4 + 2] = v.z; sT[kr][c4 + 3] = v.w;
        }
        __syncthreads();
#pragma unroll
        for (int i = 0; i < 2; ++i) {
            const int idx = i * 256 + t;
            const int nr = idx >> 3, ch = (idx & 7) * 8;
            s16x8 o;
#pragma unroll
            for (int e = 0; e < 8; ++e) o[e] = f2bf(sT[ch + e][nr]);
            *(s16x8*)(Wt + (size_t)(n0 + nr) * DIM + k0 + ch) = o;
        }
        return;
    }

    // ---- attention ----
    char* sK  = smem;                    // bf16 [key][d], swz (key&7)<<4
    char* sV  = smem + 64 * 128;         // bf16 [d][key], swz fV(d)<<4
    char* sPb = smem + 2 * 64 * 128;     // 4 x 16*128 per-wave P

    const int ab   = bid - 256;
    const int lane = t & 63;
    const int w    = t >> 6;
    const int q0   = (ab & 31) * 64;
    const int h    = ab >> 5;
    const size_t headBase = (size_t)h * T_SEQ * HD;

    const int lr = lane & 15;
    const int lg = lane >> 4;

    s16x8 qf[2];
    {
        const float* qrow = qg + headBase + (size_t)(q0 + w * 16 + lr) * HD + lg * 8;
#pragma unroll
        for (int s = 0; s < 2; ++s) {
            float4 a = *(const float4*)(qrow + 32 * s);
            float4 b = *(const float4*)(qrow + 32 * s + 4);
            s16x8 f;
            f[0] = f2bf(a.x); f[1] = f2bf(a.y); f[2] = f2bf(a.z); f[3] = f2bf(a.w);
            f[4] = f2bf(b.x); f[5] = f2bf(b.y); f[6] = f2bf(b.z); f[7] = f2bf(b.w);
            qf[s] = f;
        }
    }

    f32x4 o[4];
#pragma unroll
    for (int i = 0; i < 4; ++i) o[i] = (f32x4){0.f, 0.f, 0.f, 0.f};
    float lsum[4] = {0.f, 0.f, 0.f, 0.f};

    int lo = q0 - (WIN - 1);
    if (lo < 0) lo = 0;
    const int kc0 = lo & ~63;

    // staging geometry. K: row srow, d [sd0,sd0+16). V: keys {2kp,2kp+1}, d [dg*8,dg*8+8).
    const int srow = t >> 2;
    const int sd0  = (t & 3) * 16;
    const int kp   = t >> 3;
    const int dg   = t & 7;

    float4 kA, kB, kC, kD, vA, vB, vC, vD;   // prefetch registers (T14)
#define LOADCHUNK(kc)                                                             \
    do {                                                                          \
        const float* ks_ = kg + headBase + (size_t)((kc) + srow) * HD + sd0;      \
        kA = *(const float4*)(ks_);      kB = *(const float4*)(ks_ + 4);          \
        kC = *(const float4*)(ks_ + 8);  kD = *(const float4*)(ks_ + 12);         \
        const float* v0_ = vg + headBase + (size_t)((kc) + 2 * kp) * HD + dg * 8; \
        vA = *(const float4*)(v0_);      vB = *(const float4*)(v0_ + 4);          \
        const float* v1_ = v0_ + HD;                                              \
        vC = *(const float4*)(v1_);      vD = *(const float4*)(v1_ + 4);          \
    } while (0)

    LOADCHUNK(kc0);

    for (int kc = kc0; kc <= q0; kc += 64) {
        __syncthreads();   // previous chunk's LDS reads done before overwrite
        {
            // K [key][d]
            s16x8 c0, c1;
            c0[0] = f2bf(kA.x); c0[1] = f2bf(kA.y); c0[2] = f2bf(kA.z); c0[3] = f2bf(kA.w);
            c0[4] = f2bf(kB.x); c0[5] = f2bf(kB.y); c0[6] = f2bf(kB.z); c0[7] = f2bf(kB.w);
            c1[0] = f2bf(kC.x); c1[1] = f2bf(kC.y); c1[2] = f2bf(kC.z); c1[3] = f2bf(kC.w);
            c1[4] = f2bf(kD.x); c1[5] = f2bf(kD.y); c1[6] = f2bf(kD.z); c1[7] = f2bf(kD.w);
            const int swz = (srow & 7) << 4;
            *(s16x8*)(sK + srow * 128 + ((sd0 * 2) ^ swz))      = c0;
            *(s16x8*)(sK + srow * 128 + ((sd0 * 2 + 16) ^ swz)) = c1;

            // V^T [d][key], u32 key-pair writes
            float vlo[8] = {vA.x, vA.y, vA.z, vA.w, vB.x, vB.y, vB.z, vB.w};
            float vhi[8] = {vC.x, vC.y, vC.z, vC.w, vD.x, vD.y, vD.z, vD.w};
#pragma unroll
            for (int e = 0; e < 8; ++e) {
                const int d = dg * 8 + e;
                unsigned wv = (unsigned)f2bf(vlo[e]) | ((unsigned)f2bf(vhi[e]) << 16);
                *(unsigned*)(sV + d * 128 + ((kp * 4) ^ (fV(d) << 4))) = wv;
            }
        }
        __syncthreads();
        if (kc + 64 <= q0) LOADCHUNK(kc + 64);  // T14: land during compute below

        // ---- S = Q K^T, mask, exp, P -> per-wave LDS ----
        char* pw = sPb + w * 16 * 128;
#pragma unroll
        for (int kt = 0; kt < 4; ++kt) {
            const int krow = kt * 16 + lr;
            const int kswz = (krow & 7) << 4;
            s16x8 kf0 = *(const s16x8*)(sK + krow * 128 + ((lg * 16) ^ kswz));
            s16x8 kf1 = *(const s16x8*)(sK + krow * 128 + ((lg * 16 + 64) ^ kswz));
            f32x4 s = (f32x4){0.f, 0.f, 0.f, 0.f};
            __builtin_amdgcn_s_setprio(1);
            s = __builtin_amdgcn_mfma_f32_16x16x32_bf16(qf[0], kf0, s, 0, 0, 0);
            s = __builtin_amdgcn_mfma_f32_16x16x32_bf16(qf[1], kf1, s, 0, 0, 0);
            __builtin_amdgcn_s_setprio(0);
            const int key = kc + kt * 16 + lr;
#pragma unroll
            for (int r = 0; r < 4; ++r) {
                const int qrow = q0 + w * 16 + lg * 4 + r;
                float pv = 0.f;
                if (key <= qrow && key > qrow - WIN) pv = __expf(s[r] * 0.125f);
                lsum[r] += pv;
                const int prow = lg * 4 + r;
                *(u16*)(pw + prow * 128 + ((kt * 32 + lr * 2) ^ ((prow & 7) << 4))) = f2bf(pv);
            }
        }

        // ---- O += P V ----
        s16x8 pf0 = *(const s16x8*)(pw + lr * 128 + ((lg * 16) ^ ((lr & 7) << 4)));
        s16x8 pf1 = *(const s16x8*)(pw + lr * 128 + ((lg * 16 + 64) ^ ((lr & 7) << 4)));
        __builtin_amdgcn_s_setprio(1);
#pragma unroll
        for (int td = 0; td < 4; ++td) {
            const int drow = td * 16 + lr;
            const int vswz = fV(drow) << 4;
            s16x8 vf0 = *(const s16x8*)(sV + drow * 128 + ((lg * 16) ^ vswz));
            s16x8 vf1 = *(const s16x8*)(sV + drow * 128 + ((lg * 16 + 64) ^ vswz));
            o[td] = __builtin_amdgcn_mfma_f32_16x16x32_bf16(pf0, vf0, o[td], 0, 0, 0);
            o[td] = __builtin_amdgcn_mfma_f32_16x16x32_bf16(pf1, vf1, o[td], 0, 0, 0);
        }
        __builtin_amdgcn_s_setprio(0);
    }
#undef LOADCHUNK

#pragma unroll
    for (int m = 1; m < 16; m <<= 1) {
#pragma unroll
        for (int r = 0; r < 4; ++r) lsum[r] += __shfl_xor(lsum[r], m, 64);
    }
    float rl[4];
#pragma unroll
    for (int r = 0; r < 4; ++r) rl[r] = 1.f / lsum[r];
#pragma unroll
    for (int td = 0; td < 4; ++td)
#pragma unroll
        for (int r = 0; r < 4; ++r)
            y[(size_t)(q0 + w * 16 + lg * 4 + r) * DIM + h * HD + td * 16 + lr] =
                f2bf(o[td][r] * rl[r]);
}

// ---------------------------------------------------------------------------
// proj: out = y @ W. BM=128 BN=64 BK=64, 4 waves (2x2), wave-tile 64x32.
// grid = 256 = full chip. Triple-buffered counted-vmcnt pipeline (round-8
// version, measured ~8.5-9us):
//   STAGE(t+2) ; vmcnt(12) ; s_barrier ; ds_read+MFMA(setprio) ; s_barrier
// LDS 72KB. XCD-chunked swizzle: 2 M-panels x 16 N-panels per XCD (2.5MB L2).
// ---------------------------------------------------------------------------
__global__ __launch_bounds__(256) void proj_kernel(const u16* __restrict__ A,
                                                   const u16* __restrict__ Bt,
                                                   float* __restrict__ out) {
    __shared__ __align__(16) char sA[3][128 * 128];  // [m][k] bf16, 16KB/buf
    __shared__ __align__(16) char sB[3][64 * 128];   // [n][k] bf16,  8KB/buf

    const int t    = threadIdx.x;
    const int lane = t & 63;
    const int w    = t >> 6;
    const int wr   = w >> 1, wc = w & 1;
    const int lr   = lane & 15, lg = lane >> 4;

    // XCD-chunked bijective swizzle (nwg=256, 8 XCDs, q=32)
    const int id   = (int)blockIdx.x;
    const int wgid = (id & 7) * 32 + (id >> 3);
    const int m0   = (wgid >> 4) * 128;   // 16 M-panels
    const int n0   = (wgid & 15) * 64;    // 16 N-panels

    f32x4 acc[4][2];
#pragma unroll
    for (int i = 0; i < 4; ++i)
#pragma unroll
        for (int j = 0; j < 2; ++j) acc[i][j] = (f32x4){0.f, 0.f, 0.f, 0.f};

    const int sRow = lane >> 3;
    const int sCh  = lane & 7;

#define STAGE(buf, k0)                                                                 \
    do {                                                                               \
        _Pragma("unroll") for (int p = 0; p < 4; ++p) {                                \
            const int pi  = p * 4 + w;                                                 \
            const int row = pi * 8 + sRow;                                             \
            gload16(A + (size_t)(m0 + row) * DIM + (k0) + ((sCh ^ (row & 7)) << 3),    \
                    sA[buf] + pi * 1024);                                              \
        }                                                                              \
        _Pragma("unroll") for (int p = 0; p < 2; ++p) {                                \
            const int pi  = p * 4 + w;                                                 \
            const int row = pi * 8 + sRow;                                             \
            gload16(Bt + (size_t)(n0 + row) * DIM + (k0) + ((sCh ^ (row & 7)) << 3),   \
                    sB[buf] + pi * 1024);                                              \
        }                                                                              \
    } while (0)

    STAGE(0, 0);
    STAGE(1, 64);

#pragma unroll
    for (int kt = 0; kt < DIM / 64; ++kt) {
        const int cur  = kt % 3;
        const int nxt  = (kt + 2) % 3;
        const int knxt = ((kt + 2) & 15) * 64;  // tail wraps: stale, harmless

        STAGE(nxt, knxt);                       // dest buf reads done (kt-1 end barrier)
        asm volatile("s_waitcnt vmcnt(12)" ::: "memory");  // own tile-kt landed
        __builtin_amdgcn_s_barrier();           // => ALL waves' tile-kt landed

        s16x8 af[2][4], bfr[2][2];
#pragma unroll
        for (int kh = 0; kh < 2; ++kh) {
#pragma unroll
            for (int mi = 0; mi < 4; ++mi) {
                const int row = wr * 64 + mi * 16 + lr;
                const int cc  = kh * 4 + lg;
                af[kh][mi] = *(const s16x8*)(sA[cur] + row * 128 + ((cc ^ (row & 7)) << 4));
            }
#pragma unroll
            for (int ni = 0; ni < 2; ++ni) {
                const int row = wc * 32 + ni * 16 + lr;
                const int cc  = kh * 4 + lg;
                bfr[kh][ni] = *(const s16x8*)(sB[cur] + row * 128 + ((cc ^ (row & 7)) << 4));
            }
        }
        __builtin_amdgcn_s_setprio(1);
#pragma unroll
        for (int kh = 0; kh < 2; ++kh)
#pragma unroll
            for (int mi = 0; mi < 4; ++mi)
#pragma unroll
                for (int ni = 0; ni < 2; ++ni)
                    acc[mi][ni] = __builtin_amdgcn_mfma_f32_16x16x32_bf16(
                        af[kh][mi], bfr[kh][ni], acc[mi][ni], 0, 0, 0);
        __builtin_amdgcn_s_setprio(0);
        __builtin_amdgcn_s_barrier();           // buf[cur] reads done before overwrite
    }
#undef STAGE

    asm volatile("s_waitcnt vmcnt(0)" ::: "memory");  // drain stale tail gloads

#pragma unroll
    for (int mi = 0; mi < 4; ++mi)
#pragma unroll
        for (int ni = 0; ni < 2; ++ni)
#pragma unroll
            for (int r = 0; r < 4; ++r)
                out[(size_t)(m0 + wr * 64 + mi * 16 + lg * 4 + r) * DIM +
                    n0 + wc * 32 + ni * 16 + lr] = acc[mi][ni][r];
}

extern "C" void kernel_launch(void* const* d_in, const int* in_sizes, int n_in,
                              void* d_out, int out_size, void* d_ws, size_t ws_size,
                              hipStream_t stream) {
    const float* q = (const float*)d_in[0];
    const float* k = (const float*)d_in[1];
    const float* v = (const float*)d_in[2];
    const float* W = (const float*)d_in[3];
    float* out = (float*)d_out;
    u16* y_bf = (u16*)d_ws;                       // (T, DIM) bf16 = 4MB
    u16* Wt   = (u16*)d_ws + (size_t)T_SEQ * DIM; // (DIM, DIM) bf16 = 2MB

    prep_kernel<<<768, 256, 0, stream>>>(W, Wt, q, k, v, y_bf);
    proj_kernel<<<256, 256, 0, stream>>>(y_bf, Wt, out);
}